// Round 6
// baseline (434.717 us; speedup 1.0000x reference)
//
#include <hip/hip_runtime.h>
#include <stdint.h>

typedef unsigned long long u64;
typedef unsigned int u32;
typedef int i32x4 __attribute__((ext_vector_type(4)));

#define HW 65536            // 256*256
#define WD 256
#define ROWB (258 * 64)     // bytes per padded sx row = 16512
#define RS (258 * ROWB)     // bytes per padded sx frame = 4260096

// ---------------------------------------------------------------------------
// Kernel 1: pack weights as i8 +-1 into sw[tap][o][c] (+ scale[o]).
// ---------------------------------------------------------------------------
__global__ __launch_bounds__(64) void pack_w2(const float* __restrict__ wt,
                                              char* __restrict__ sw,
                                              float* __restrict__ scale) {
    const int o = blockIdx.x;
    const int c = threadIdx.x;
    const float* p = wt + o * 576 + c * 9;
    float s = 0.f;
#pragma unroll
    for (int k = 0; k < 9; k++) {
        const u32 u = __float_as_uint(p[k]);
        s += fabsf(p[k]);
        sw[k * 4096 + o * 64 + c] = (char)(1 + (((int)u >> 31) & 0xFE)); // +1 / -1
    }
#pragma unroll
    for (int off = 32; off > 0; off >>= 1) s += __shfl_down(s, off);
    if (c == 0) scale[o] = s * (1.0f / 576.0f);
}

// ---------------------------------------------------------------------------
// Kernel 2: zero the top/bottom padded border rows of sx (rows 0 and 257).
// Side columns are zeroed inside pack_x2. Zero i8 == conv zero-padding.
// ---------------------------------------------------------------------------
__global__ __launch_bounds__(320) void zero_tb(char* __restrict__ sx) {
    const int n = blockIdx.x >> 1;
    const int row = (blockIdx.x & 1) * 257;
    const int t = threadIdx.x;
    if (t < 258) {
        uint4 z = make_uint4(0, 0, 0, 0);
        uint4* d = (uint4*)(sx + (size_t)n * RS + (size_t)row * ROWB + t * 64);
        d[0] = z; d[1] = z; d[2] = z; d[3] = z;
    }
}

// ---------------------------------------------------------------------------
// Kernel 3: pack activations (with temporal channel shift) as i8 +-1 into
// padded sx[n][258][258][64], c innermost. Block = (4-row band, n); wave per
// row; lane packs 4 cols; c processed in 4 chunks of 16 (chunk-uniform source
// frame). Also zeroes the side-column borders of its rows.
// ---------------------------------------------------------------------------
__global__ __launch_bounds__(256) void pack_x2(const float* __restrict__ x,
                                               char* __restrict__ sx) {
    const int band = blockIdx.x;        // 0..63
    const int n = blockIdx.y;           // 0..11
    const int wv = threadIdx.x >> 6;
    const int lane = threadIdx.x & 63;
    const int r = (band << 2) + wv;     // image row 0..255

    const int b = n / 3;
    const int t = n - b * 3;
    const int fp = b * 3 + (t + 2) % 3;

    // y-channel c: c<32 -> x[fp][32+c]; c>=32 -> x[n][c-32]
    const float* xa = x + ((size_t)fp * 64 + 32) * HW + r * WD + (lane << 2);
    const float* xb = x + (size_t)n * 64 * HW + r * WD + (lane << 2);

    char* dstrow = sx + (size_t)n * RS + (size_t)(r + 1) * ROWB;

#pragma unroll
    for (int cc = 0; cc < 4; cc++) {
        const float* base = (cc < 2) ? (xa + (size_t)(cc * 16) * HW)
                                     : (xb + (size_t)((cc - 2) * 16) * HW);
        u32 w0[4] = {0, 0, 0, 0}, w1[4] = {0, 0, 0, 0};
        u32 w2[4] = {0, 0, 0, 0}, w3[4] = {0, 0, 0, 0};
#pragma unroll
        for (int ci = 0; ci < 16; ci++) {
            float4 v = *(const float4*)(base + (size_t)ci * HW);
            const int sh = (ci & 3) * 8;
            const int wi = ci >> 2;
            w0[wi] |= (1u + ((u32)((int)__float_as_uint(v.x) >> 31) & 0xFEu)) << sh;
            w1[wi] |= (1u + ((u32)((int)__float_as_uint(v.y) >> 31) & 0xFEu)) << sh;
            w2[wi] |= (1u + ((u32)((int)__float_as_uint(v.z) >> 31) & 0xFEu)) << sh;
            w3[wi] |= (1u + ((u32)((int)__float_as_uint(v.w) >> 31) & 0xFEu)) << sh;
        }
        char* d = dstrow + (size_t)((lane << 2) + 1) * 64 + cc * 16;
        *(uint4*)(d)       = make_uint4(w0[0], w0[1], w0[2], w0[3]);
        *(uint4*)(d + 64)  = make_uint4(w1[0], w1[1], w1[2], w1[3]);
        *(uint4*)(d + 128) = make_uint4(w2[0], w2[1], w2[2], w2[3]);
        *(uint4*)(d + 192) = make_uint4(w3[0], w3[1], w3[2], w3[3]);
    }

    // side-column borders (col 0 and col 257) for this block's 4 rows
    if (threadIdx.x < 8) {
        const int rr = (band << 2) + (threadIdx.x >> 1) + 1;   // sx row 1..256
        const int col = (threadIdx.x & 1) * 257;
        uint4 z = make_uint4(0, 0, 0, 0);
        uint4* d = (uint4*)(sx + (size_t)n * RS + (size_t)rr * ROWB + (size_t)col * 64);
        d[0] = z; d[1] = z; d[2] = z; d[3] = z;
    }
}

// ---------------------------------------------------------------------------
// Kernel 4: conv via i8 MFMA. out[n][o][h][w] = scale[o] * sum(+-1 products).
// Block = (gh row, n), 4 waves, wave owns 64 px. A = weights (M=16 o), held in
// 144 VGPRs for all 4 o-groups x 9 taps; B = activations (N=16 px) loaded per
// px-group as perfectly-coalesced 1 KB reads from L2-hot sx. No LDS, no
// barriers, no edge corrections (sx zero-pad). Regular cacheable stores
// (L2 write-combining) instead of nontemporal.
// A-frag: lane holds row m=lane&15, k-bytes (lane>>4)*16+[0,16).
// B-frag: lane holds col n=lane&15, same k split.
// D: col(n)=lane&15, row(m)=(lane>>4)*4+reg  [guide-verified, shape-determined]
// ---------------------------------------------------------------------------
__global__ __launch_bounds__(256, 2) void conv_mfma(const char* __restrict__ sx,
                                                    const char* __restrict__ sw,
                                                    const float* __restrict__ scale,
                                                    float* __restrict__ out) {
    const int bx = blockIdx.x;                      // 0..255
    const int n = blockIdx.y;                       // 0..11
    const int gh = ((bx & 7) << 5) | (bx >> 3);     // XCD k -> rows [32k,32k+32)
    const int lane = threadIdx.x & 63;
    const int wv = threadIdx.x >> 6;
    const int lr = lane & 15;
    const int q = lane >> 4;

    // persistent weight fragments: a[og][tap]
    i32x4 a[4][9];
#pragma unroll
    for (int og = 0; og < 4; og++)
#pragma unroll
        for (int tap = 0; tap < 9; tap++)
            a[og][tap] = *(const i32x4*)(sw + (size_t)(tap * 64 + og * 16 + lr) * 64 + q * 16);

    // per-lane output scales: row m = q*4+reg within o-group
    float sc[4][4];
#pragma unroll
    for (int og = 0; og < 4; og++)
#pragma unroll
        for (int reg = 0; reg < 4; reg++)
            sc[og][reg] = scale[og * 16 + q * 4 + reg];

    const char* sxn = sx + (size_t)n * RS;
    float* ob = out + (size_t)n * 64 * HW + gh * WD;
    const int px0w = wv << 6;

#pragma unroll
    for (int pxg = 0; pxg < 4; pxg++) {
        const int px0 = px0w + (pxg << 4);
        i32x4 bfr[9];
#pragma unroll
        for (int tr = 0; tr < 3; tr++)
#pragma unroll
            for (int tc = 0; tc < 3; tc++)
                bfr[tr * 3 + tc] = *(const i32x4*)(sxn
                    + (size_t)(gh + tr) * ROWB
                    + (size_t)(px0 + lr + tc) * 64 + q * 16);

#pragma unroll
        for (int og = 0; og < 4; og++) {
            i32x4 acc = {0, 0, 0, 0};
#pragma unroll
            for (int tap = 0; tap < 9; tap++)
                acc = __builtin_amdgcn_mfma_i32_16x16x64_i8(a[og][tap], bfr[tap], acc, 0, 0, 0);
#pragma unroll
            for (int reg = 0; reg < 4; reg++) {
                const int o = og * 16 + q * 4 + reg;
                ob[(size_t)o * HW + px0 + lr] = sc[og][reg] * (float)acc[reg];
            }
        }
    }
}

// ---------------------------------------------------------------------------
extern "C" void kernel_launch(void* const* d_in, const int* in_sizes, int n_in,
                              void* d_out, int out_size, void* d_ws, size_t ws_size,
                              hipStream_t stream) {
    (void)in_sizes; (void)n_in; (void)out_size; (void)ws_size;
    const float* x  = (const float*)d_in[0];
    const float* wt = (const float*)d_in[1];
    float* out = (float*)d_out;

    // workspace: sx (12*RS = 51.12 MB i8) | sw (9*64*64 i8) | scale (64 f32)
    char* sx = (char*)d_ws;
    char* sw = sx + (size_t)12 * RS;
    float* scale = (float*)(sw + 9 * 4096);

    pack_w2<<<64, 64, 0, stream>>>(wt, sw, scale);
    zero_tb<<<24, 320, 0, stream>>>(sx);
    pack_x2<<<dim3(64, 12), 256, 0, stream>>>(x, sx);
    conv_mfma<<<dim3(256, 12), 256, 0, stream>>>(sx, sw, scale, out);
}

// Round 7
// 357.310 us; speedup vs baseline: 1.2166x; 1.2166x over previous
//
#include <hip/hip_runtime.h>
#include <stdint.h>

typedef unsigned long long u64;
typedef unsigned int u32;
typedef int i32x4 __attribute__((ext_vector_type(4)));

#define HW 65536            // 256*256
#define WD 256
#define LROWB 16384         // 256 px * 64 B per LDS row

// ---------------------------------------------------------------------------
// Kernel 1: pack weights as i8 +-1 into sw[tap][o][c] (+ scale[o]).
// (verified round 6)
// ---------------------------------------------------------------------------
__global__ __launch_bounds__(64) void pack_w2(const float* __restrict__ wt,
                                              char* __restrict__ sw,
                                              float* __restrict__ scale) {
    const int o = blockIdx.x;
    const int c = threadIdx.x;
    const float* p = wt + o * 576 + c * 9;
    float s = 0.f;
#pragma unroll
    for (int k = 0; k < 9; k++) {
        const u32 u = __float_as_uint(p[k]);
        s += fabsf(p[k]);
        sw[k * 4096 + o * 64 + c] = (char)(1 + (((int)u >> 31) & 0xFE)); // +1 / -1
    }
#pragma unroll
    for (int off = 32; off > 0; off >>= 1) s += __shfl_down(s, off);
    if (c == 0) scale[o] = s * (1.0f / 576.0f);
}

// ---------------------------------------------------------------------------
// Kernel 2 (single FUSED pack+MFMA-conv):
// block = 2 output rows x 256 cols x all 64 o; 512 threads; LDS 64 KiB
// (4 input rows x 256 px x 64B sign-bytes) -> 2 blocks/CU, 16 waves/CU.
//
// Phase 1: wave (r=wv>>1, s=wv&1) packs image row gh0-1+r, channel half s:
//   32 x 1KB coalesced float4 row-loads -> sign bytes -> LDS, with 16B-slot
//   XOR swizzle (slot ^= (px>>2)&3) to keep LDS writes AND the phase-2
//   B-frag reads at <=2-way bank conflict. OOB rows -> zeros.
// Phase 2: wave (pq=wv&3 px-quarter, oh=wv>>2 o-pair): weights for 2 o-groups
//   in 72 VGPRs (loaded once, L2-hot); per 16-px group stream 3 B-frags per
//   tap-row from LDS, 18 MFMAs (2 indep acc chains); col-edge taps zeroed
//   per-lane (cndmask), row edges by zeroed LDS rows -> no pad, no aux.
// XCD band swizzle keeps adjacent bands (shared halo rows) in one L2.
// ---------------------------------------------------------------------------
__global__ __launch_bounds__(512, 4) void fused_mfma(const float* __restrict__ x,
                                                     const char* __restrict__ sw,
                                                     const float* __restrict__ scale,
                                                     float* __restrict__ out) {
    __shared__ __align__(16) char lds[4 * LROWB];   // 65536 B

    const int bx = blockIdx.x;                      // 0..127
    const int n  = blockIdx.y;                      // 0..11
    const int band = ((bx & 7) << 4) | (bx >> 3);   // XCD k -> bands [16k,16k+16)
    const int gh0 = band << 1;

    const int b = n / 3;
    const int t = n - b * 3;
    const int fp = b * 3 + (t + 2) % 3;             // source frame for y-ch 0..31

    const int tid  = threadIdx.x;
    const int lane = tid & 63;
    const int wv   = tid >> 6;                      // 0..7
    const int q    = lane >> 4;                     // 0..3
    const int lr   = lane & 15;

    // ---- phase 1: pack 4 input rows (gh0-1 .. gh0+2) into LDS ----
    {
        const int r  = wv >> 1;                     // lds row 0..3
        const int s  = wv & 1;                      // channel half
        const int ir = gh0 - 1 + r;                 // image row -1..256

        u32 st[4][8];
#pragma unroll
        for (int j = 0; j < 4; j++)
#pragma unroll
            for (int k = 0; k < 8; k++) st[j][k] = 0;

        if ((ir >= 0) & (ir < 256)) {               // wave-uniform
            // y-channel c: c<32 -> x[fp][32+c]; c>=32 -> x[n][c-32]
            const float* src = s ? (x + (size_t)n * 64 * HW)
                                 : (x + ((size_t)fp * 64 + 32) * HW);
            const float* p = src + (size_t)ir * WD + (lane << 2);
#pragma unroll
            for (int c = 0; c < 32; c++) {          // 1 KB contiguous per load
                float4 v = *(const float4*)(p + (size_t)c * HW);
                const int wi = c >> 2;
                const int sh = (c & 3) * 8;
                st[0][wi] |= (1u + (((u32)((int)__float_as_uint(v.x) >> 31)) & 0xFEu)) << sh;
                st[1][wi] |= (1u + (((u32)((int)__float_as_uint(v.y) >> 31)) & 0xFEu)) << sh;
                st[2][wi] |= (1u + (((u32)((int)__float_as_uint(v.z) >> 31)) & 0xFEu)) << sh;
                st[3][wi] |= (1u + (((u32)((int)__float_as_uint(v.w) >> 31)) & 0xFEu)) << sh;
            }
        }
        const int sw2 = lane & 3;                   // == (px>>2)&3 for px=4*lane+j
#pragma unroll
        for (int j = 0; j < 4; j++) {
            char* dbase = lds + r * LROWB + (((lane << 2) + j) << 6);
#pragma unroll
            for (int tt = 0; tt < 2; tt++) {
                const int swz = ((s << 1) + tt) ^ sw2;
                i32x4 val = {(int)st[j][tt * 4 + 0], (int)st[j][tt * 4 + 1],
                             (int)st[j][tt * 4 + 2], (int)st[j][tt * 4 + 3]};
                *(i32x4*)(dbase + (swz << 4)) = val;
            }
        }
    }

    // ---- phase-2 operand prefetch (issued pre-barrier; consumed after) ----
    const int pq = wv & 3;                          // px-quarter
    const int oh = wv >> 2;                         // o-pair (o 0..31 / 32..63)
    i32x4 a[2][9];
#pragma unroll
    for (int j = 0; j < 2; j++) {
        const int og = oh * 2 + j;
#pragma unroll
        for (int tap = 0; tap < 9; tap++)
            a[j][tap] = *(const i32x4*)(sw + (size_t)(tap * 4096 + (og * 16 + lr) * 64 + (q << 4)));
    }
    float4 s4[2];
#pragma unroll
    for (int j = 0; j < 2; j++)
        s4[j] = *(const float4*)(scale + (oh << 5) + (j << 4) + (q << 2));

    __syncthreads();

    // ---- phase 2: conv via i8 MFMA ----
    const int rl = pq >> 1;                         // output row within block
    const int colbase = (pq & 1) << 7;
    const int gh = gh0 + rl;
    float* ob = out + (size_t)n * 64 * HW + (size_t)gh * WD;

#pragma unroll 1
    for (int pxg = 0; pxg < 8; pxg++) {
        const int cc0 = colbase + (pxg << 4);
        const int c = cc0 + lr;                     // output col 0..255
        const int cm  = (c == 0)   ? 0   : c - 1;
        const int cp2 = (c == 255) ? 255 : c + 1;
        const bool zl = (c == 0);
        const bool zr = (c == 255);

        i32x4 acc0 = {0, 0, 0, 0}, acc1 = {0, 0, 0, 0};
#pragma unroll
        for (int tr = 0; tr < 3; tr++) {
            const char* rb = lds + (rl + tr) * LROWB;
            i32x4 f0 = *(const i32x4*)(rb + (cm  << 6) + (((q ^ ((cm  >> 2) & 3))) << 4));
            i32x4 f1 = *(const i32x4*)(rb + (c   << 6) + (((q ^ ((c   >> 2) & 3))) << 4));
            i32x4 f2 = *(const i32x4*)(rb + (cp2 << 6) + (((q ^ ((cp2 >> 2) & 3))) << 4));
            if (zl) f0 = (i32x4){0, 0, 0, 0};
            if (zr) f2 = (i32x4){0, 0, 0, 0};
            acc0 = __builtin_amdgcn_mfma_i32_16x16x64_i8(a[0][tr * 3 + 0], f0, acc0, 0, 0, 0);
            acc1 = __builtin_amdgcn_mfma_i32_16x16x64_i8(a[1][tr * 3 + 0], f0, acc1, 0, 0, 0);
            acc0 = __builtin_amdgcn_mfma_i32_16x16x64_i8(a[0][tr * 3 + 1], f1, acc0, 0, 0, 0);
            acc1 = __builtin_amdgcn_mfma_i32_16x16x64_i8(a[1][tr * 3 + 1], f1, acc1, 0, 0, 0);
            acc0 = __builtin_amdgcn_mfma_i32_16x16x64_i8(a[0][tr * 3 + 2], f2, acc0, 0, 0, 0);
            acc1 = __builtin_amdgcn_mfma_i32_16x16x64_i8(a[1][tr * 3 + 2], f2, acc1, 0, 0, 0);
        }

        const float* sc0 = (const float*)&s4[0];
        const float* sc1 = (const float*)&s4[1];
#pragma unroll
        for (int reg = 0; reg < 4; reg++) {
            const int o0 = (oh << 5) + (q << 2) + reg;
            ob[(size_t)o0 * HW + c]        = sc0[reg] * (float)acc0[reg];
            ob[(size_t)(o0 + 16) * HW + c] = sc1[reg] * (float)acc1[reg];
        }
    }
}

// ---------------------------------------------------------------------------
extern "C" void kernel_launch(void* const* d_in, const int* in_sizes, int n_in,
                              void* d_out, int out_size, void* d_ws, size_t ws_size,
                              hipStream_t stream) {
    (void)in_sizes; (void)n_in; (void)out_size; (void)ws_size;
    const float* x  = (const float*)d_in[0];
    const float* wt = (const float*)d_in[1];
    float* out = (float*)d_out;

    // workspace: sw (9*64*64 i8 = 36 KiB) | scale (64 f32)
    char* sw = (char*)d_ws;
    float* scale = (float*)(sw + 9 * 4096);

    pack_w2<<<64, 64, 0, stream>>>(wt, sw, scale);
    fused_mfma<<<dim3(128, 12), 512, 0, stream>>>(x, sw, scale, out);
}